// Round 3
// baseline (1155.435 us; speedup 1.0000x reference)
//
#include <hip/hip_runtime.h>
#include <math.h>

#define IMN 1024
#define IMGSZ (IMN * IMN)
#define NIMG 6
#define EPSV 0.001f
#define NB1 4096

typedef unsigned short u16;
typedef __attribute__((ext_vector_type(8))) short short8;     // 8 bf16 = 4 VGPRs
typedef __attribute__((ext_vector_type(16))) float floatx16;  // 32x32 C/D

__device__ __forceinline__ u16 rne_bf16(float v) {
  unsigned u = __float_as_uint(v);
  u = u + 0x7FFFu + ((u >> 16) & 1u);
  return (u16)(u >> 16);
}

// ---------------------------------------------------------------------------
__global__ __launch_bounds__(256) void build_taps_k(float* __restrict__ taps) {
  const int kss[3] = {91, 481, 1501};
  const float sig[3] = {15.f, 80.f, 250.f};
  int s = blockIdx.x;
  int ks = kss[s];
  float sigma = sig[s];
  float* t = taps + s * 1536;
  float ctr = (float)(ks - 1) * 0.5f;
  __shared__ float red[256];
  float loc = 0.f;
  for (int i = threadIdx.x; i < ks; i += 256) {
    float x = ((float)i - ctr) / sigma;
    float v = expf(-0.5f * x * x);
    t[i] = v;
    loc += v;
  }
  red[threadIdx.x] = loc;
  __syncthreads();
  for (int o = 128; o > 0; o >>= 1) {
    if (threadIdx.x < o) red[threadIdx.x] += red[threadIdx.x + o];
    __syncthreads();
  }
  float inv = 1.f / red[0];
  for (int i = threadIdx.x; i < ks; i += 256) t[i] *= inv;
}

// ---------------------------------------------------------------------------
// W[r,j] = sum of taps with reflect(r+t-p)==j; stored as bf16 hi (RNE) + lo (RNE resid).
// NOTE: support(W[r,.]) is exactly contained in [max(0,r-p), min(1023,r+p)]:
// reflected tails fold back inside that window once clamped to [0,1023].
// Outside it W is exact 0.0 in BOTH hi and lo -> gemm may skip those K ranges bit-exactly.
__global__ __launch_bounds__(256) void build_w_k(const float* __restrict__ taps, int ks,
                                                 u16* __restrict__ WHr, u16* __restrict__ WLr) {
  int r = blockIdx.x;
  int p = ks >> 1;
  __shared__ float row[IMN];
  for (int i = threadIdx.x; i < IMN; i += 256) row[i] = 0.f;
  __syncthreads();
  for (int t = threadIdx.x; t < ks; t += 256) {
    int q = r + t - p;
    int j = q < 0 ? -q : (q > IMN - 1 ? 2 * (IMN - 1) - q : q);
    atomicAdd(&row[j], taps[t]);
  }
  __syncthreads();
  for (int i = threadIdx.x; i < IMN; i += 256) {
    float v = row[i];
    u16 h = rne_bf16(v);
    float hf = __uint_as_float((unsigned)h << 16);
    WHr[r * IMN + i] = h;
    WLr[r * IMN + i] = rne_bf16(v - hf);
  }
}

// ---------------------------------------------------------------------------
// clip(img) -> single bf16 (RNE) plane (A is hi-only; validated in round 6).
__global__ __launch_bounds__(256) void split_img_k(const float* __restrict__ inp,
                                                   u16* __restrict__ H) {
  int i4 = (blockIdx.x * 256 + threadIdx.x) * 4;
  float4 v = *(const float4*)&inp[i4];
  float x[4] = {v.x, v.y, v.z, v.w};
  u16 h[4];
#pragma unroll
  for (int e = 0; e < 4; e++) h[e] = rne_bf16(fminf(fmaxf(x[e], EPSV), 1.f));
  *(uint2*)&H[i4] = make_uint2((unsigned)h[0] | ((unsigned)h[1] << 16),
                               (unsigned)h[2] | ((unsigned)h[3] << 16));
}

// ---------------------------------------------------------------------------
// bf16x2 MFMA GEMM (A-hi x (B-hi + B-lo)), 128x128 tile, 32x32x16, wave 64x64.
// ROUND-7: band-limited K loop (exact; see build_w_k note).
// ROUND-9 (this): round-1 reg-staging structure (proven 63.2us/gemm; the
//   gload_lds 2-phase graft regressed to 67.5 -- vmcnt(0) barrier drain,
//   m131-m141 null reproduced) with three residual costs removed:
//   (a) LDS linear [128][32] + BOTH-SIDES XOR swizzle (verified in round 2):
//       phys_slot = logical_slot ^ ((row>>1)&3), applied at ds_write (staging)
//       and ds_read (frags). Bank-quad = (4*row + phys_slot) mod 8 -> uniform
//       8 lanes/quad on b128 = conflict-minimal. Replaces LDK=40 pad (4-way
//       frag conflict). LDS 30720 -> 24576 B.
//   (b) __launch_bounds__(256,6): LDS now allows 6 blocks/CU (VGPR ~68 << 85).
//   (c) epilogue __syncthreads removed: lf is per-wave-private; last k-loop
//       barrier already fences cross-wave frag reads.
// SQ_LDS_BANK_CONFLICT ~4.09M is free 2-way bookkeeping (identical across
// structures, scales exactly with k-steps) -- not a cost signal.
// EPI=0: A = imgH[i], B = WH/WL[s]; out OH[z] = bf16 U, stored transposed.
// EPI=1: A = UtH[z],  B = WH/WL[s]; out OF[outByZ? z : i] = log(max(blur,eps)).
template <int EPI>
__global__ __launch_bounds__(256, 6) void gemm_pass(
    const u16* __restrict__ AH, const u16* __restrict__ WH, const u16* __restrict__ WL,
    u16* __restrict__ OH, float* __restrict__ OF, int sBase, int outByZ, int rmw) {
  __shared__ u16 smem[3 * 128 * 32];  // 24576 B -> 6 blocks/CU
  u16* Ah = smem;
  u16* Bh = smem + 128 * 32;
  u16* Bl = smem + 2 * 128 * 32;
  int z = blockIdx.z;
  int zs = z / 6;
  int s = (gridDim.z >= 18) ? (sBase + 2 - zs) : (sBase + zs);  // heavy-first
  int i = z - zs * 6;
  const u16* Ag = AH + (size_t)(EPI == 0 ? i : z) * IMGSZ;
  const u16* BgH = WH + (size_t)s * IMGSZ;
  const u16* BgL = WL + (size_t)s * IMGSZ;
  int bm = blockIdx.y * 128, bn = blockIdx.x * 128;
  int tid = threadIdx.x;
  int lane = tid & 63, w = tid >> 6;
  int wm = (w >> 1) * 64, wn = (w & 1) * 64;
  int lrow = lane & 31, lh = lane >> 5;
  int sig = (lrow >> 1) & 3;              // frag-read swizzle key
  int tr = tid >> 2;                      // staging row 0..63 (and +64)
  int tc = (tid & 3) * 8;                 // linear global col offset (u16)
  int sslot = ((tid & 3) ^ ((tr >> 1) & 3)) * 8;  // swizzled LDS slot offset
  // note: sig(tr) == sig(tr+64): bit 6 doesn't touch bits 1-2.
  floatx16 acc[2][2] = {};

  // Band-limited K window (exact: W is 0.0 outside).
  int p = (s == 0) ? 45 : (s == 1) ? 240 : 750;
  int klo = bn - p;
  klo = (klo < 0 ? 0 : klo) & ~31;
  int khi = bn + 128 + p;
  if (khi > IMN) khi = IMN;

  for (int k0 = klo; k0 < khi; k0 += 32) {
    uint4 a0 = *(const uint4*)&Ag[(size_t)(bm + tr) * IMN + k0 + tc];
    uint4 a1 = *(const uint4*)&Ag[(size_t)(bm + tr + 64) * IMN + k0 + tc];
    uint4 b0h = *(const uint4*)&BgH[(size_t)(bn + tr) * IMN + k0 + tc];
    uint4 b1h = *(const uint4*)&BgH[(size_t)(bn + tr + 64) * IMN + k0 + tc];
    uint4 b0l = *(const uint4*)&BgL[(size_t)(bn + tr) * IMN + k0 + tc];
    uint4 b1l = *(const uint4*)&BgL[(size_t)(bn + tr + 64) * IMN + k0 + tc];
    *(uint4*)&Ah[tr * 32 + sslot] = a0;
    *(uint4*)&Ah[(tr + 64) * 32 + sslot] = a1;
    *(uint4*)&Bh[tr * 32 + sslot] = b0h;
    *(uint4*)&Bh[(tr + 64) * 32 + sslot] = b1h;
    *(uint4*)&Bl[tr * 32 + sslot] = b0l;
    *(uint4*)&Bl[(tr + 64) * 32 + sslot] = b1l;
    __syncthreads();
#pragma unroll
    for (int kk = 0; kk < 32; kk += 16) {
      int sl = (kk >> 3) + lh;            // logical 16B slot 0..3
      int so = ((sl ^ sig) * 8);          // swizzled read offset (u16)
      short8 ah[2], bh[2], bl[2];
#pragma unroll
      for (int mt = 0; mt < 2; mt++)
        ah[mt] = *(const short8*)&Ah[(wm + mt * 32 + lrow) * 32 + so];
#pragma unroll
      for (int nt2 = 0; nt2 < 2; nt2++) {
        int off = (wn + nt2 * 32 + lrow) * 32 + so;
        bh[nt2] = *(const short8*)&Bh[off];
        bl[nt2] = *(const short8*)&Bl[off];
      }
#pragma unroll
      for (int mt = 0; mt < 2; mt++)
#pragma unroll
        for (int nt2 = 0; nt2 < 2; nt2++) {
          acc[mt][nt2] = __builtin_amdgcn_mfma_f32_32x32x16_bf16(ah[mt], bh[nt2], acc[mt][nt2], 0, 0, 0);
          acc[mt][nt2] = __builtin_amdgcn_mfma_f32_32x32x16_bf16(ah[mt], bl[nt2], acc[mt][nt2], 0, 0, 0);
        }
    }
    __syncthreads();
  }

  // Epilogue (round-5 proven mapping): per-wave 32x32 LDS transpose (stride 33),
  // coalesced row stores. C/D: col(n)=lane&31, row(m)=(reg&3)+8*(reg>>2)+4*(lane>>5).
  // lf is PER-WAVE private -> no block barriers needed (intra-wave DS ordering
  // is enforced by compiler lgkmcnt waits).
  float* lf = (float*)smem + w * 1056;  // 4 x 4224 B = 16896 <= 24576
#pragma unroll
  for (int mt = 0; mt < 2; mt++)
#pragma unroll
    for (int nt = 0; nt < 2; nt++) {
#pragma unroll
      for (int rq = 0; rq < 4; rq++)
#pragma unroll
        for (int e = 0; e < 4; e++)
          lf[lrow * 33 + rq * 8 + lh * 4 + e] = acc[mt][nt][rq * 4 + e];
#pragma unroll
      for (int p4 = 0; p4 < 4; p4++) {
        int rl = p4 * 8 + (lane >> 3);
        int cl = (lane & 7) * 4;
        float v0 = lf[rl * 33 + cl + 0];
        float v1 = lf[rl * 33 + cl + 1];
        float v2 = lf[rl * 33 + cl + 2];
        float v3 = lf[rl * 33 + cl + 3];
        int gn = bn + wn + nt * 32 + rl;  // output row
        int gm = bm + wm + mt * 32 + cl;  // output col
        if (EPI == 0) {
          size_t go = (size_t)z * IMGSZ + (size_t)gn * IMN + gm;  // keep plane offset!
          *(uint2*)&OH[go] = make_uint2(
              (unsigned)rne_bf16(v0) | ((unsigned)rne_bf16(v1) << 16),
              (unsigned)rne_bf16(v2) | ((unsigned)rne_bf16(v3) << 16));
        } else {
          size_t go = (size_t)(outByZ ? z : i) * IMGSZ + (size_t)gn * IMN + gm;
          float4 rr = make_float4(logf(fmaxf(v0, EPSV)), logf(fmaxf(v1, EPSV)),
                                  logf(fmaxf(v2, EPSV)), logf(fmaxf(v3, EPSV)));
          if (rmw) {
            float4 pa = *(const float4*)&OF[go];
            rr.x += pa.x; rr.y += pa.y; rr.z += pa.z; rr.w += pa.w;
          }
          *(float4*)&OF[go] = rr;
        }
      }
    }
}

// ---------------------------------------------------------------------------
__global__ __launch_bounds__(256) void loss_stage1_k(const float* __restrict__ inp,
                                                     const float* __restrict__ lb, int three,
                                                     float* __restrict__ refl,
                                                     float* __restrict__ illum,
                                                     float* __restrict__ pd,
                                                     float* __restrict__ ps) {
  const int stride = NB1 * 256;
  const int S = NIMG * IMGSZ;
  float sd = 0.f, ss = 0.f;
  for (int i = blockIdx.x * 256 + threadIdx.x; i < S; i += stride) {
    int c = i & (IMN - 1);
    int rr = (i >> 10) & (IMN - 1);
    float a0 = lb[i];
    if (three) a0 += lb[i + S] + lb[i + 2 * S];
    float I0 = a0 * (1.f / 3.f);
    float R0 = logf(fmaxf(inp[i], EPSV)) - I0;
    refl[i] = R0;
    illum[i] = I0;
    if (c < IMN - 1) {
      float a1 = lb[i + 1];
      if (three) a1 += lb[i + 1 + S] + lb[i + 1 + 2 * S];
      float I1 = a1 * (1.f / 3.f);
      float R1 = logf(fmaxf(inp[i + 1], EPSV)) - I1;
      sd += fabsf(R0 - R1);
      ss += fabsf(I0 - I1);
    }
    if (rr < IMN - 1) {
      float a2 = lb[i + IMN];
      if (three) a2 += lb[i + IMN + S] + lb[i + IMN + 2 * S];
      float I2 = a2 * (1.f / 3.f);
      float R2 = logf(fmaxf(inp[i + IMN], EPSV)) - I2;
      sd += fabsf(R0 - R2);
      ss += fabsf(I0 - I2);
    }
  }
  for (int o = 32; o > 0; o >>= 1) {
    sd += __shfl_down(sd, o);
    ss += __shfl_down(ss, o);
  }
  __shared__ float rsd[4], rss[4];
  int lane = threadIdx.x & 63, w = threadIdx.x >> 6;
  if (lane == 0) { rsd[w] = sd; rss[w] = ss; }
  __syncthreads();
  if (threadIdx.x == 0) {
    pd[blockIdx.x] = rsd[0] + rsd[1] + rsd[2] + rsd[3];
    ps[blockIdx.x] = rss[0] + rss[1] + rss[2] + rss[3];
  }
}

__global__ __launch_bounds__(256) void loss_stage2_k(const float* __restrict__ pd,
                                                     const float* __restrict__ ps,
                                                     float* __restrict__ out) {
  float sd = 0.f, ss = 0.f;
  for (int i = threadIdx.x; i < NB1; i += 256) {
    sd += pd[i];
    ss += ps[i];
  }
  for (int o = 32; o > 0; o >>= 1) {
    sd += __shfl_down(sd, o);
    ss += __shfl_down(ss, o);
  }
  __shared__ float rsd[4], rss[4];
  int lane = threadIdx.x & 63, w = threadIdx.x >> 6;
  if (lane == 0) { rsd[w] = sd; rss[w] = ss; }
  __syncthreads();
  if (threadIdx.x == 0) {
    float tsd = rsd[0] + rsd[1] + rsd[2] + rsd[3];
    float tss = rss[0] + rss[1] + rss[2] + rss[3];
    const float sc = 1.f / 6285312.f;  // 2*3*1024*1023
    out[0] = tss * sc;
    out[1] = tsd * sc;
    out[2] = tss * sc;
  }
}

// ---------------------------------------------------------------------------
extern "C" void kernel_launch(void* const* d_in, const int* in_sizes, int n_in,
                              void* d_out, int out_size, void* d_ws, size_t ws_size,
                              hipStream_t stream) {
  const float* inp = (const float*)d_in[0];
  float* out = (float*)d_out;
  float* refl = out + 3;
  float* illum = refl + (size_t)NIMG * IMGSZ;
  const int kss[3] = {91, 481, 1501};

  char* p = (char*)d_ws;
  float* taps = (float*)p;                  p += 32768;
  u16* WH = (u16*)p;                        p += (size_t)3 * IMGSZ * 2;
  u16* WL = (u16*)p;                        p += (size_t)3 * IMGSZ * 2;
  u16* imgH = (u16*)p;                      p += (size_t)NIMG * IMGSZ * 2;
  size_t fixed = (size_t)(p - (char*)d_ws);
  // Tier1 (z=18, one dispatch/pass): Ut 18 bf16 planes (36 MB) + LB 18 fp32 (72 MB).
  size_t needT1 = fixed + (size_t)18 * IMGSZ * 2 + (size_t)18 * IMGSZ * 4;
  bool t1 = ws_size >= needT1;
  int nz = t1 ? 18 : 6;
  u16* UtH = (u16*)p;                       p += (size_t)nz * IMGSZ * 2;
  float* LB = (float*)p;  // t1: 18 log-blur planes; t2: 6-plane fp32 accumulator
  float* pd = taps;       // overlay dead taps region
  float* ps = taps + NB1;

  build_taps_k<<<3, 256, 0, stream>>>(taps);
  for (int s = 0; s < 3; s++)
    build_w_k<<<IMN, 256, 0, stream>>>(taps + s * 1536, kss[s],
                                       WH + (size_t)s * IMGSZ, WL + (size_t)s * IMGSZ);
  split_img_k<<<NIMG * IMGSZ / 1024, 256, 0, stream>>>(inp, imgH);

  if (t1) {
    dim3 g(8, 8, 18);
    gemm_pass<0><<<g, 256, 0, stream>>>(imgH, WH, WL, UtH, nullptr, 0, 1, 0);
    gemm_pass<1><<<g, 256, 0, stream>>>(UtH, WH, WL, nullptr, LB, 0, 1, 0);
  } else {
    dim3 g(8, 8, 6);
    for (int s = 0; s < 3; s++) {
      gemm_pass<0><<<g, 256, 0, stream>>>(imgH, WH, WL, UtH, nullptr, s, 0, 0);
      gemm_pass<1><<<g, 256, 0, stream>>>(UtH, WH, WL, nullptr, LB, s, 0, s > 0);
    }
  }
  loss_stage1_k<<<NB1, 256, 0, stream>>>(inp, LB, t1 ? 1 : 0, refl, illum, pd, ps);
  loss_stage2_k<<<1, 256, 0, stream>>>(pd, ps, out);
}

// Round 4
// 261.335 us; speedup vs baseline: 4.4213x; 4.4213x over previous
//
#include <hip/hip_runtime.h>
#include <math.h>

#define IMN 1024
#define IMGSZ (IMN * IMN)
#define NIMG 6
#define EPSV 0.001f
#define NB1 4096

typedef unsigned short u16;
typedef __attribute__((ext_vector_type(8))) short short8;     // 8 bf16 = 4 VGPRs
typedef __attribute__((ext_vector_type(16))) float floatx16;  // 32x32 C/D

__device__ __forceinline__ u16 rne_bf16(float v) {
  unsigned u = __float_as_uint(v);
  u = u + 0x7FFFu + ((u >> 16) & 1u);
  return (u16)(u >> 16);
}

// ---------------------------------------------------------------------------
__global__ __launch_bounds__(256) void build_taps_k(float* __restrict__ taps) {
  const int kss[3] = {91, 481, 1501};
  const float sig[3] = {15.f, 80.f, 250.f};
  int s = blockIdx.x;
  int ks = kss[s];
  float sigma = sig[s];
  float* t = taps + s * 1536;
  float ctr = (float)(ks - 1) * 0.5f;
  __shared__ float red[256];
  float loc = 0.f;
  for (int i = threadIdx.x; i < ks; i += 256) {
    float x = ((float)i - ctr) / sigma;
    float v = expf(-0.5f * x * x);
    t[i] = v;
    loc += v;
  }
  red[threadIdx.x] = loc;
  __syncthreads();
  for (int o = 128; o > 0; o >>= 1) {
    if (threadIdx.x < o) red[threadIdx.x] += red[threadIdx.x + o];
    __syncthreads();
  }
  float inv = 1.f / red[0];
  for (int i = threadIdx.x; i < ks; i += 256) t[i] *= inv;
}

// ---------------------------------------------------------------------------
// W[r,j] = sum of taps with reflect(r+t-p)==j; stored as bf16 hi (RNE) + lo (RNE resid).
// NOTE: support(W[r,.]) is exactly contained in [max(0,r-p), min(1023,r+p)]:
// reflected tails fold back inside that window once clamped to [0,1023].
// Outside it W is exact 0.0 in BOTH hi and lo -> gemm may skip those K ranges bit-exactly.
__global__ __launch_bounds__(256) void build_w_k(const float* __restrict__ taps, int ks,
                                                 u16* __restrict__ WHr, u16* __restrict__ WLr) {
  int r = blockIdx.x;
  int p = ks >> 1;
  __shared__ float row[IMN];
  for (int i = threadIdx.x; i < IMN; i += 256) row[i] = 0.f;
  __syncthreads();
  for (int t = threadIdx.x; t < ks; t += 256) {
    int q = r + t - p;
    int j = q < 0 ? -q : (q > IMN - 1 ? 2 * (IMN - 1) - q : q);
    atomicAdd(&row[j], taps[t]);
  }
  __syncthreads();
  for (int i = threadIdx.x; i < IMN; i += 256) {
    float v = row[i];
    u16 h = rne_bf16(v);
    float hf = __uint_as_float((unsigned)h << 16);
    WHr[r * IMN + i] = h;
    WLr[r * IMN + i] = rne_bf16(v - hf);
  }
}

// ---------------------------------------------------------------------------
// clip(img) -> single bf16 (RNE) plane (A is hi-only; validated in round 6).
__global__ __launch_bounds__(256) void split_img_k(const float* __restrict__ inp,
                                                   u16* __restrict__ H) {
  int i4 = (blockIdx.x * 256 + threadIdx.x) * 4;
  float4 v = *(const float4*)&inp[i4];
  float x[4] = {v.x, v.y, v.z, v.w};
  u16 h[4];
#pragma unroll
  for (int e = 0; e < 4; e++) h[e] = rne_bf16(fminf(fmaxf(x[e], EPSV), 1.f));
  *(uint2*)&H[i4] = make_uint2((unsigned)h[0] | ((unsigned)h[1] << 16),
                               (unsigned)h[2] | ((unsigned)h[3] << 16));
}

// ---------------------------------------------------------------------------
// bf16x2 MFMA GEMM (A-hi x (B-hi + B-lo)), 128x128 tile, 32x32x16, wave 64x64.
// ROUND-7: band-limited K loop (exact; see build_w_k note).
// ROUND-10 (this): EXACT round-1 structure -- (256,4), reg-staging, epilogue
//   WITH barriers (round-3's (256,6) + barrier-free epilogue spilled acc to
//   scratch: VGPR 40, 2.3GB scratch traffic, 9x regression; lesson: never
//   raise min-waves on an MFMA kernel with acc+frags near the budget) --
//   with ONE isolated change vs round 1:
//   LDS linear [128][32] + BOTH-SIDES XOR swizzle replacing the LDK=40 pad:
//     phys_slot = logical_slot ^ ((row>>1)&3)  at ds_write AND ds_read.
//     Bank-quad = (4*row + phys_slot) mod 8 -> uniform 8 lanes/quad on b128.
//     Mapping refcheck-passed in rounds 2 and 3. LDS 30720 -> 24576 B.
//   A/B question: was LDK=40's 4-way frag-read conflict a real cost?
// SQ_LDS_BANK_CONFLICT is bit-identical (4,091,904) across 3 different LDS
// layouts incl. DMA staging -> inherent 2-way bookkeeping, NOT a cost signal.
// EPI=0: A = imgH[i], B = WH/WL[s]; out OH[z] = bf16 U, stored transposed.
// EPI=1: A = UtH[z],  B = WH/WL[s]; out OF[outByZ? z : i] = log(max(blur,eps)).
template <int EPI>
__global__ __launch_bounds__(256, 4) void gemm_pass(
    const u16* __restrict__ AH, const u16* __restrict__ WH, const u16* __restrict__ WL,
    u16* __restrict__ OH, float* __restrict__ OF, int sBase, int outByZ, int rmw) {
  __shared__ u16 smem[3 * 128 * 32];  // 24576 B
  u16* Ah = smem;
  u16* Bh = smem + 128 * 32;
  u16* Bl = smem + 2 * 128 * 32;
  int z = blockIdx.z;
  int zs = z / 6;
  int s = (gridDim.z >= 18) ? (sBase + 2 - zs) : (sBase + zs);  // heavy-first
  int i = z - zs * 6;
  const u16* Ag = AH + (size_t)(EPI == 0 ? i : z) * IMGSZ;
  const u16* BgH = WH + (size_t)s * IMGSZ;
  const u16* BgL = WL + (size_t)s * IMGSZ;
  int bm = blockIdx.y * 128, bn = blockIdx.x * 128;
  int tid = threadIdx.x;
  int lane = tid & 63, w = tid >> 6;
  int wm = (w >> 1) * 64, wn = (w & 1) * 64;
  int lrow = lane & 31, lh = lane >> 5;
  int sig = (lrow >> 1) & 3;              // frag-read swizzle key
  int tr = tid >> 2;                      // staging row 0..63 (and +64)
  int tc = (tid & 3) * 8;                 // linear global col offset (u16)
  int sslot = ((tid & 3) ^ ((tr >> 1) & 3)) * 8;  // swizzled LDS slot offset
  // note: sig(tr) == sig(tr+64): bit 6 doesn't touch bits 1-2.
  floatx16 acc[2][2] = {};

  // Band-limited K window (exact: W is 0.0 outside).
  int p = (s == 0) ? 45 : (s == 1) ? 240 : 750;
  int klo = bn - p;
  klo = (klo < 0 ? 0 : klo) & ~31;
  int khi = bn + 128 + p;
  if (khi > IMN) khi = IMN;

  for (int k0 = klo; k0 < khi; k0 += 32) {
    uint4 a0 = *(const uint4*)&Ag[(size_t)(bm + tr) * IMN + k0 + tc];
    uint4 a1 = *(const uint4*)&Ag[(size_t)(bm + tr + 64) * IMN + k0 + tc];
    uint4 b0h = *(const uint4*)&BgH[(size_t)(bn + tr) * IMN + k0 + tc];
    uint4 b1h = *(const uint4*)&BgH[(size_t)(bn + tr + 64) * IMN + k0 + tc];
    uint4 b0l = *(const uint4*)&BgL[(size_t)(bn + tr) * IMN + k0 + tc];
    uint4 b1l = *(const uint4*)&BgL[(size_t)(bn + tr + 64) * IMN + k0 + tc];
    *(uint4*)&Ah[tr * 32 + sslot] = a0;
    *(uint4*)&Ah[(tr + 64) * 32 + sslot] = a1;
    *(uint4*)&Bh[tr * 32 + sslot] = b0h;
    *(uint4*)&Bh[(tr + 64) * 32 + sslot] = b1h;
    *(uint4*)&Bl[tr * 32 + sslot] = b0l;
    *(uint4*)&Bl[(tr + 64) * 32 + sslot] = b1l;
    __syncthreads();
#pragma unroll
    for (int kk = 0; kk < 32; kk += 16) {
      int sl = (kk >> 3) + lh;            // logical 16B slot 0..3
      int so = ((sl ^ sig) * 8);          // swizzled read offset (u16)
      short8 ah[2], bh[2], bl[2];
#pragma unroll
      for (int mt = 0; mt < 2; mt++)
        ah[mt] = *(const short8*)&Ah[(wm + mt * 32 + lrow) * 32 + so];
#pragma unroll
      for (int nt2 = 0; nt2 < 2; nt2++) {
        int off = (wn + nt2 * 32 + lrow) * 32 + so;
        bh[nt2] = *(const short8*)&Bh[off];
        bl[nt2] = *(const short8*)&Bl[off];
      }
#pragma unroll
      for (int mt = 0; mt < 2; mt++)
#pragma unroll
        for (int nt2 = 0; nt2 < 2; nt2++) {
          acc[mt][nt2] = __builtin_amdgcn_mfma_f32_32x32x16_bf16(ah[mt], bh[nt2], acc[mt][nt2], 0, 0, 0);
          acc[mt][nt2] = __builtin_amdgcn_mfma_f32_32x32x16_bf16(ah[mt], bl[nt2], acc[mt][nt2], 0, 0, 0);
        }
    }
    __syncthreads();
  }

  // Epilogue (round-5 proven): per-wave 32x32 LDS transpose (stride 33),
  // coalesced row stores. C/D: col(n)=lane&31, row(m)=(reg&3)+8*(reg>>2)+4*(lane>>5).
  float* lf = (float*)smem + w * 1056;  // 4 x 4224 B = 16896 <= 24576
#pragma unroll
  for (int mt = 0; mt < 2; mt++)
#pragma unroll
    for (int nt = 0; nt < 2; nt++) {
#pragma unroll
      for (int rq = 0; rq < 4; rq++)
#pragma unroll
        for (int e = 0; e < 4; e++)
          lf[lrow * 33 + rq * 8 + lh * 4 + e] = acc[mt][nt][rq * 4 + e];
      __syncthreads();
#pragma unroll
      for (int p4 = 0; p4 < 4; p4++) {
        int rl = p4 * 8 + (lane >> 3);
        int cl = (lane & 7) * 4;
        float v0 = lf[rl * 33 + cl + 0];
        float v1 = lf[rl * 33 + cl + 1];
        float v2 = lf[rl * 33 + cl + 2];
        float v3 = lf[rl * 33 + cl + 3];
        int gn = bn + wn + nt * 32 + rl;  // output row
        int gm = bm + wm + mt * 32 + cl;  // output col
        if (EPI == 0) {
          size_t go = (size_t)z * IMGSZ + (size_t)gn * IMN + gm;  // keep plane offset!
          *(uint2*)&OH[go] = make_uint2(
              (unsigned)rne_bf16(v0) | ((unsigned)rne_bf16(v1) << 16),
              (unsigned)rne_bf16(v2) | ((unsigned)rne_bf16(v3) << 16));
        } else {
          size_t go = (size_t)(outByZ ? z : i) * IMGSZ + (size_t)gn * IMN + gm;
          float4 rr = make_float4(logf(fmaxf(v0, EPSV)), logf(fmaxf(v1, EPSV)),
                                  logf(fmaxf(v2, EPSV)), logf(fmaxf(v3, EPSV)));
          if (rmw) {
            float4 pa = *(const float4*)&OF[go];
            rr.x += pa.x; rr.y += pa.y; rr.z += pa.z; rr.w += pa.w;
          }
          *(float4*)&OF[go] = rr;
        }
      }
      __syncthreads();
    }
}

// ---------------------------------------------------------------------------
__global__ __launch_bounds__(256) void loss_stage1_k(const float* __restrict__ inp,
                                                     const float* __restrict__ lb, int three,
                                                     float* __restrict__ refl,
                                                     float* __restrict__ illum,
                                                     float* __restrict__ pd,
                                                     float* __restrict__ ps) {
  const int stride = NB1 * 256;
  const int S = NIMG * IMGSZ;
  float sd = 0.f, ss = 0.f;
  for (int i = blockIdx.x * 256 + threadIdx.x; i < S; i += stride) {
    int c = i & (IMN - 1);
    int rr = (i >> 10) & (IMN - 1);
    float a0 = lb[i];
    if (three) a0 += lb[i + S] + lb[i + 2 * S];
    float I0 = a0 * (1.f / 3.f);
    float R0 = logf(fmaxf(inp[i], EPSV)) - I0;
    refl[i] = R0;
    illum[i] = I0;
    if (c < IMN - 1) {
      float a1 = lb[i + 1];
      if (three) a1 += lb[i + 1 + S] + lb[i + 1 + 2 * S];
      float I1 = a1 * (1.f / 3.f);
      float R1 = logf(fmaxf(inp[i + 1], EPSV)) - I1;
      sd += fabsf(R0 - R1);
      ss += fabsf(I0 - I1);
    }
    if (rr < IMN - 1) {
      float a2 = lb[i + IMN];
      if (three) a2 += lb[i + IMN + S] + lb[i + IMN + 2 * S];
      float I2 = a2 * (1.f / 3.f);
      float R2 = logf(fmaxf(inp[i + IMN], EPSV)) - I2;
      sd += fabsf(R0 - R2);
      ss += fabsf(I0 - I2);
    }
  }
  for (int o = 32; o > 0; o >>= 1) {
    sd += __shfl_down(sd, o);
    ss += __shfl_down(ss, o);
  }
  __shared__ float rsd[4], rss[4];
  int lane = threadIdx.x & 63, w = threadIdx.x >> 6;
  if (lane == 0) { rsd[w] = sd; rss[w] = ss; }
  __syncthreads();
  if (threadIdx.x == 0) {
    pd[blockIdx.x] = rsd[0] + rsd[1] + rsd[2] + rsd[3];
    ps[blockIdx.x] = rss[0] + rss[1] + rss[2] + rss[3];
  }
}

__global__ __launch_bounds__(256) void loss_stage2_k(const float* __restrict__ pd,
                                                     const float* __restrict__ ps,
                                                     float* __restrict__ out) {
  float sd = 0.f, ss = 0.f;
  for (int i = threadIdx.x; i < NB1; i += 256) {
    sd += pd[i];
    ss += ps[i];
  }
  for (int o = 32; o > 0; o >>= 1) {
    sd += __shfl_down(sd, o);
    ss += __shfl_down(ss, o);
  }
  __shared__ float rsd[4], rss[4];
  int lane = threadIdx.x & 63, w = threadIdx.x >> 6;
  if (lane == 0) { rsd[w] = sd; rss[w] = ss; }
  __syncthreads();
  if (threadIdx.x == 0) {
    float tsd = rsd[0] + rsd[1] + rsd[2] + rsd[3];
    float tss = rss[0] + rss[1] + rss[2] + rss[3];
    const float sc = 1.f / 6285312.f;  // 2*3*1024*1023
    out[0] = tss * sc;
    out[1] = tsd * sc;
    out[2] = tss * sc;
  }
}

// ---------------------------------------------------------------------------
extern "C" void kernel_launch(void* const* d_in, const int* in_sizes, int n_in,
                              void* d_out, int out_size, void* d_ws, size_t ws_size,
                              hipStream_t stream) {
  const float* inp = (const float*)d_in[0];
  float* out = (float*)d_out;
  float* refl = out + 3;
  float* illum = refl + (size_t)NIMG * IMGSZ;
  const int kss[3] = {91, 481, 1501};

  char* p = (char*)d_ws;
  float* taps = (float*)p;                  p += 32768;
  u16* WH = (u16*)p;                        p += (size_t)3 * IMGSZ * 2;
  u16* WL = (u16*)p;                        p += (size_t)3 * IMGSZ * 2;
  u16* imgH = (u16*)p;                      p += (size_t)NIMG * IMGSZ * 2;
  size_t fixed = (size_t)(p - (char*)d_ws);
  // Tier1 (z=18, one dispatch/pass): Ut 18 bf16 planes (36 MB) + LB 18 fp32 (72 MB).
  size_t needT1 = fixed + (size_t)18 * IMGSZ * 2 + (size_t)18 * IMGSZ * 4;
  bool t1 = ws_size >= needT1;
  int nz = t1 ? 18 : 6;
  u16* UtH = (u16*)p;                       p += (size_t)nz * IMGSZ * 2;
  float* LB = (float*)p;  // t1: 18 log-blur planes; t2: 6-plane fp32 accumulator
  float* pd = taps;       // overlay dead taps region
  float* ps = taps + NB1;

  build_taps_k<<<3, 256, 0, stream>>>(taps);
  for (int s = 0; s < 3; s++)
    build_w_k<<<IMN, 256, 0, stream>>>(taps + s * 1536, kss[s],
                                       WH + (size_t)s * IMGSZ, WL + (size_t)s * IMGSZ);
  split_img_k<<<NIMG * IMGSZ / 1024, 256, 0, stream>>>(inp, imgH);

  if (t1) {
    dim3 g(8, 8, 18);
    gemm_pass<0><<<g, 256, 0, stream>>>(imgH, WH, WL, UtH, nullptr, 0, 1, 0);
    gemm_pass<1><<<g, 256, 0, stream>>>(UtH, WH, WL, nullptr, LB, 0, 1, 0);
  } else {
    dim3 g(8, 8, 6);
    for (int s = 0; s < 3; s++) {
      gemm_pass<0><<<g, 256, 0, stream>>>(imgH, WH, WL, UtH, nullptr, s, 0, 0);
      gemm_pass<1><<<g, 256, 0, stream>>>(UtH, WH, WL, nullptr, LB, s, 0, s > 0);
    }
  }
  loss_stage1_k<<<NB1, 256, 0, stream>>>(inp, LB, t1 ? 1 : 0, refl, illum, pd, ps);
  loss_stage2_k<<<1, 256, 0, stream>>>(pd, ps, out);
}